// Round 1
// baseline (2818.720 us; speedup 1.0000x reference)
//
#include <hip/hip_runtime.h>

#define N_ATOM 30000
#define N_PAIR 1000000
#define N_TRI  4000000
#define N_SF   16
#define FP_ELEMS (N_ATOM * N_SF)   // 480000 floats
// jacob region: 2*N_PAIR elements following fp region

__device__ __constant__ float c_eta[16] = {
    0.01f, 0.014f, 0.02f, 0.028f, 0.04f, 0.056f, 0.08f, 0.11f,
    0.16f, 0.22f, 0.32f, 0.45f, 0.63f, 0.72f, 0.9f, 1.0f};

// Kernel 1: initialize d_out (poisoned 0xAA before every timed launch).
// fp region -> 0.0f ; jac odd slots (pair_i accumulator) -> -1 (int32)
__global__ __launch_bounds__(256) void init_kernel(float* __restrict__ out) {
    int i = blockIdx.x * blockDim.x + threadIdx.x;
    if (i < FP_ELEMS) out[i] = 0.0f;
    if (i < N_PAIR) {
        int* jac = (int*)out + FP_ELEMS;
        jac[2 * i + 1] = -1;
    }
}

// Kernel 2: one thread per triplet.
__global__ __launch_bounds__(256) void tri_kernel(
    const int* __restrict__ ind2,    // (N_PAIR,2) int32
    const int2* __restrict__ ind3,   // (N_TRI,2) int32
    const float* __restrict__ dist,  // (N_PAIR,)
    const float* __restrict__ diff,  // (N_PAIR,3)
    const float* __restrict__ fc,    // (N_PAIR,)
    float* __restrict__ out)
{
    int t = blockIdx.x * blockDim.x + threadIdx.x;
    if (t >= N_TRI) return;

    int2 pr = ind3[t];
    int ij = pr.x;
    int ik = pr.y;

    // gather displacement vectors
    float ax = diff[3 * ij + 0];
    float ay = diff[3 * ij + 1];
    float az = diff[3 * ij + 2];
    float bx = diff[3 * ik + 0];
    float by = diff[3 * ik + 1];
    float bz = diff[3 * ik + 2];

    float jx = bx - ax, jy = by - ay, jz = bz - az;
    float d2jk = jx * jx + jy * jy + jz * jz;
    float djk = sqrtf(d2jk);

    // masked triplets contribute nothing to fp, and -1 (no-op vs init) to pair_i
    if (!(djk < 6.0f)) return;

    int atom = ind2[2 * ij];  // i_rind = ind_2[ij, 0]

    // segment-max contributions (both pair slots of this triplet)
    int* jac = (int*)out + FP_ELEMS;
    atomicMax(&jac[2 * ij + 1], atom);
    atomicMax(&jac[2 * ik + 1], atom);

    float dij = dist[ij];
    float dik = dist[ik];
    float fcij = fc[ij];
    float fcik = fc[ik];

    const float PI_OVER_RC = 0.5235987755982988f;
    float fcjk = 0.5f * (__cosf(PI_OVER_RC * djk) + 1.0f);

    float cosv = (ax * bx + ay * by + az * bz) / (dij * dik);
    float R2 = fmaf(dij, dij, fmaf(dik, dik, d2jk));
    float FCt = fcij * fcik * fcjk;

    float bm = fmaxf(1.0f - cosv, 0.0f);
    float bp = fmaxf(1.0f + cosv, 0.0f);
    float bm2 = bm * bm, bp2 = bp * bp;
    float bm4 = bm2 * bm2, bp4 = bp2 * bp2;
    float bm8 = bm4 * bm4, bp8 = bp4 * bp4;

    // A[s&7] = 2^(1-zeta_s) * base^zeta_s * FCt  (lambda=-1 even s, +1 odd s)
    float A[8];
    A[0] = FCt * bm;
    A[1] = FCt * bp;
    A[2] = 0.5f * FCt * bm2;
    A[3] = 0.5f * FCt * bp2;
    A[4] = 0.125f * FCt * bm4;
    A[5] = 0.125f * FCt * bp4;
    A[6] = 0.0078125f * FCt * bm8;
    A[7] = 0.0078125f * FCt * bp8;

    float* base = out + atom * N_SF;
#pragma unroll
    for (int s = 0; s < 16; ++s) {
        float v = A[s & 7] * __expf(-c_eta[s] * R2);
        unsafeAtomicAdd(base + s, v);  // HW global_atomic_add_f32
    }
}

// Kernel 3: convert pair_i to float, write arange column.
__global__ __launch_bounds__(256) void fin_kernel(float* __restrict__ out) {
    int p = blockIdx.x * blockDim.x + threadIdx.x;
    if (p >= N_PAIR) return;
    int* jac = (int*)out + FP_ELEMS;
    int v = jac[2 * p + 1];
    float* jf = (float*)jac;
    jf[2 * p + 0] = (float)p;
    jf[2 * p + 1] = (float)v;
}

extern "C" void kernel_launch(void* const* d_in, const int* in_sizes, int n_in,
                              void* d_out, int out_size, void* d_ws, size_t ws_size,
                              hipStream_t stream) {
    const int*   ind2 = (const int*)d_in[0];
    const int2*  ind3 = (const int2*)d_in[1];
    const float* dist = (const float*)d_in[2];
    const float* diff = (const float*)d_in[3];
    // d_in[4] = elems (unused by reference)
    const float* fc   = (const float*)d_in[5];
    float* out = (float*)d_out;

    init_kernel<<<(N_PAIR + 255) / 256, 256, 0, stream>>>(out);
    tri_kernel<<<(N_TRI + 255) / 256, 256, 0, stream>>>(ind2, ind3, dist, diff, fc, out);
    fin_kernel<<<(N_PAIR + 255) / 256, 256, 0, stream>>>(out);
}

// Round 2
// 545.238 us; speedup vs baseline: 5.1697x; 5.1697x over previous
//
#include <hip/hip_runtime.h>

#define N_ATOM 30000
#define N_PAIR 1000000
#define N_TRI  4000000
#define N_SF   16
#define FP_ELEMS (N_ATOM * N_SF)   // 480000 floats
#define CAP 256                     // bucket capacity per atom (mean 133, sigma ~11.5)

__device__ __constant__ float c_eta[16] = {
    0.01f, 0.014f, 0.02f, 0.028f, 0.04f, 0.056f, 0.08f, 0.11f,
    0.16f, 0.22f, 0.32f, 0.45f, 0.63f, 0.72f, 0.9f, 1.0f};

// ---------------------------------------------------------------------------
// Fast path kernels (binning + per-atom wave reduction)
// ---------------------------------------------------------------------------

// init: zero bucket counters, set jac odd slots to -1
__global__ __launch_bounds__(256) void init2_kernel(float* __restrict__ out,
                                                    int* __restrict__ cnt) {
    int i = blockIdx.x * blockDim.x + threadIdx.x;
    if (i < N_ATOM) cnt[i] = 0;
    if (i < N_PAIR) {
        int* jac = (int*)out + FP_ELEMS;
        jac[2 * i + 1] = -1;
    }
}

// repack {diff.xyz, dist, fc} into 32B-aligned records: one cache line per gather
__global__ __launch_bounds__(256) void pack_kernel(
    const float* __restrict__ dist, const float* __restrict__ diff,
    const float* __restrict__ fc, float4* __restrict__ pack) {
    int p = blockIdx.x * blockDim.x + threadIdx.x;
    if (p >= N_PAIR) return;
    float4 a;
    a.x = diff[3 * p + 0];
    a.y = diff[3 * p + 1];
    a.z = diff[3 * p + 2];
    a.w = dist[p];
    float4 b;
    b.x = fc[p];
    b.y = 0.f; b.z = 0.f; b.w = 0.f;
    pack[2 * p + 0] = a;
    pack[2 * p + 1] = b;
}

// bin: scatter triplet (ij,ik) into its atom's bucket
__global__ __launch_bounds__(256) void bin_kernel(
    const int* __restrict__ ind2, const int2* __restrict__ ind3,
    int* __restrict__ cnt, int2* __restrict__ bucket) {
    int t = blockIdx.x * blockDim.x + threadIdx.x;
    if (t >= N_TRI) return;
    int2 pr = ind3[t];
    int atom = ind2[2 * pr.x];
    int slot = atomicAdd(&cnt[atom], 1);
    if (slot < CAP) bucket[(size_t)atom * CAP + slot] = pr;
}

// reduce: one wave per atom. Accumulate 16 channels in registers, shuffle-reduce,
// single 64B store. Also does the jac atomicMax (8M ops).
template <bool PACKED>
__global__ __launch_bounds__(256) void reduce_kernel(
    const int* __restrict__ cnt, const int2* __restrict__ bucket,
    const float4* __restrict__ pack,
    const float* __restrict__ dist, const float* __restrict__ diff,
    const float* __restrict__ fc, float* __restrict__ out) {
    int wave = (blockIdx.x * blockDim.x + threadIdx.x) >> 6;
    int lane = threadIdx.x & 63;
    if (wave >= N_ATOM) return;
    int atom = wave;
    int n = cnt[atom];
    if (n > CAP) n = CAP;
    const int2* seg = bucket + (size_t)atom * CAP;
    int* jac = (int*)out + FP_ELEMS;

    float acc[16];
#pragma unroll
    for (int s = 0; s < 16; ++s) acc[s] = 0.0f;

    for (int i = lane; i < n; i += 64) {
        int2 pr = seg[i];
        int ij = pr.x, ik = pr.y;
        float ax, ay, az, dij, fcij, bx, by, bz, dik, fcik;
        if (PACKED) {
            float4 A = pack[2 * ij], Fj = pack[2 * ij + 1];
            float4 B = pack[2 * ik], Fk = pack[2 * ik + 1];
            ax = A.x; ay = A.y; az = A.z; dij = A.w; fcij = Fj.x;
            bx = B.x; by = B.y; bz = B.z; dik = B.w; fcik = Fk.x;
        } else {
            ax = diff[3 * ij + 0]; ay = diff[3 * ij + 1]; az = diff[3 * ij + 2];
            bx = diff[3 * ik + 0]; by = diff[3 * ik + 1]; bz = diff[3 * ik + 2];
            dij = dist[ij]; dik = dist[ik];
            fcij = fc[ij]; fcik = fc[ik];
        }
        float jx = bx - ax, jy = by - ay, jz = bz - az;
        float d2jk = jx * jx + jy * jy + jz * jz;
        float djk = sqrtf(d2jk);
        if (!(djk < 6.0f)) continue;

        atomicMax(&jac[2 * ij + 1], atom);
        atomicMax(&jac[2 * ik + 1], atom);

        const float PI_OVER_RC = 0.5235987755982988f;
        float fcjk = 0.5f * (__cosf(PI_OVER_RC * djk) + 1.0f);
        float cosv = (ax * bx + ay * by + az * bz) / (dij * dik);
        float R2 = fmaf(dij, dij, fmaf(dik, dik, d2jk));
        float FCt = fcij * fcik * fcjk;

        float bm = fmaxf(1.0f - cosv, 0.0f);
        float bp = fmaxf(1.0f + cosv, 0.0f);
        float bm2 = bm * bm, bp2 = bp * bp;
        float bm4 = bm2 * bm2, bp4 = bp2 * bp2;
        float bm8 = bm4 * bm4, bp8 = bp4 * bp4;

        float A8[8];
        A8[0] = FCt * bm;
        A8[1] = FCt * bp;
        A8[2] = 0.5f * FCt * bm2;
        A8[3] = 0.5f * FCt * bp2;
        A8[4] = 0.125f * FCt * bm4;
        A8[5] = 0.125f * FCt * bp4;
        A8[6] = 0.0078125f * FCt * bm8;
        A8[7] = 0.0078125f * FCt * bp8;

#pragma unroll
        for (int s = 0; s < 16; ++s)
            acc[s] += A8[s & 7] * __expf(-c_eta[s] * R2);
    }

    // butterfly reduce each channel across the 64 lanes
#pragma unroll
    for (int s = 0; s < 16; ++s) {
        float v = acc[s];
#pragma unroll
        for (int o = 32; o > 0; o >>= 1) v += __shfl_down(v, o);
        acc[s] = v;
    }
    if (lane == 0) {
        float4* dst = (float4*)(out + (size_t)atom * N_SF);
        dst[0] = make_float4(acc[0], acc[1], acc[2], acc[3]);
        dst[1] = make_float4(acc[4], acc[5], acc[6], acc[7]);
        dst[2] = make_float4(acc[8], acc[9], acc[10], acc[11]);
        dst[3] = make_float4(acc[12], acc[13], acc[14], acc[15]);
    }
}

// finalize jacob_ind: col0 = arange, col1 = (float)pair_i
__global__ __launch_bounds__(256) void fin_kernel(float* __restrict__ out) {
    int p = blockIdx.x * blockDim.x + threadIdx.x;
    if (p >= N_PAIR) return;
    int* jac = (int*)out + FP_ELEMS;
    int v = jac[2 * p + 1];
    float* jf = (float*)jac;
    jf[2 * p + 0] = (float)p;
    jf[2 * p + 1] = (float)v;
}

// ---------------------------------------------------------------------------
// Fallback path (round-1 kernels) if ws_size is too small
// ---------------------------------------------------------------------------

__global__ __launch_bounds__(256) void init_kernel(float* __restrict__ out) {
    int i = blockIdx.x * blockDim.x + threadIdx.x;
    if (i < FP_ELEMS) out[i] = 0.0f;
    if (i < N_PAIR) {
        int* jac = (int*)out + FP_ELEMS;
        jac[2 * i + 1] = -1;
    }
}

__global__ __launch_bounds__(256) void tri_kernel(
    const int* __restrict__ ind2, const int2* __restrict__ ind3,
    const float* __restrict__ dist, const float* __restrict__ diff,
    const float* __restrict__ fc, float* __restrict__ out) {
    int t = blockIdx.x * blockDim.x + threadIdx.x;
    if (t >= N_TRI) return;
    int2 pr = ind3[t];
    int ij = pr.x, ik = pr.y;
    float ax = diff[3 * ij + 0], ay = diff[3 * ij + 1], az = diff[3 * ij + 2];
    float bx = diff[3 * ik + 0], by = diff[3 * ik + 1], bz = diff[3 * ik + 2];
    float jx = bx - ax, jy = by - ay, jz = bz - az;
    float d2jk = jx * jx + jy * jy + jz * jz;
    float djk = sqrtf(d2jk);
    if (!(djk < 6.0f)) return;
    int atom = ind2[2 * ij];
    int* jac = (int*)out + FP_ELEMS;
    atomicMax(&jac[2 * ij + 1], atom);
    atomicMax(&jac[2 * ik + 1], atom);
    float dij = dist[ij], dik = dist[ik];
    float fcij = fc[ij], fcik = fc[ik];
    const float PI_OVER_RC = 0.5235987755982988f;
    float fcjk = 0.5f * (__cosf(PI_OVER_RC * djk) + 1.0f);
    float cosv = (ax * bx + ay * by + az * bz) / (dij * dik);
    float R2 = fmaf(dij, dij, fmaf(dik, dik, d2jk));
    float FCt = fcij * fcik * fcjk;
    float bm = fmaxf(1.0f - cosv, 0.0f);
    float bp = fmaxf(1.0f + cosv, 0.0f);
    float bm2 = bm * bm, bp2 = bp * bp;
    float bm4 = bm2 * bm2, bp4 = bp2 * bp2;
    float bm8 = bm4 * bm4, bp8 = bp4 * bp4;
    float A8[8];
    A8[0] = FCt * bm;  A8[1] = FCt * bp;
    A8[2] = 0.5f * FCt * bm2;  A8[3] = 0.5f * FCt * bp2;
    A8[4] = 0.125f * FCt * bm4;  A8[5] = 0.125f * FCt * bp4;
    A8[6] = 0.0078125f * FCt * bm8;  A8[7] = 0.0078125f * FCt * bp8;
    float* base = out + atom * N_SF;
#pragma unroll
    for (int s = 0; s < 16; ++s) {
        float v = A8[s & 7] * __expf(-c_eta[s] * R2);
        unsafeAtomicAdd(base + s, v);
    }
}

// ---------------------------------------------------------------------------

extern "C" void kernel_launch(void* const* d_in, const int* in_sizes, int n_in,
                              void* d_out, int out_size, void* d_ws, size_t ws_size,
                              hipStream_t stream) {
    const int*   ind2 = (const int*)d_in[0];
    const int2*  ind3 = (const int2*)d_in[1];
    const float* dist = (const float*)d_in[2];
    const float* diff = (const float*)d_in[3];
    const float* fc   = (const float*)d_in[5];
    float* out = (float*)d_out;

    // ws layout: [cnt: 128KB][bucket: N_ATOM*CAP*8 B][pack: 32MB (optional)]
    const size_t CNT_BYTES = 131072;
    const size_t BUCKET_BYTES = (size_t)N_ATOM * CAP * sizeof(int2);  // 61.44 MB
    const size_t PACK_BYTES = (size_t)N_PAIR * 2 * sizeof(float4);    // 32 MB
    const size_t NEED_UNPACKED = CNT_BYTES + BUCKET_BYTES;
    const size_t NEED_PACKED = NEED_UNPACKED + PACK_BYTES;

    if (ws_size >= NEED_UNPACKED) {
        int* cnt = (int*)d_ws;
        int2* bucket = (int2*)((char*)d_ws + CNT_BYTES);
        float4* pack = (float4*)((char*)d_ws + CNT_BYTES + BUCKET_BYTES);
        bool packed = (ws_size >= NEED_PACKED);

        init2_kernel<<<(N_PAIR + 255) / 256, 256, 0, stream>>>(out, cnt);
        if (packed)
            pack_kernel<<<(N_PAIR + 255) / 256, 256, 0, stream>>>(dist, diff, fc, pack);
        bin_kernel<<<(N_TRI + 255) / 256, 256, 0, stream>>>(ind2, ind3, cnt, bucket);
        int rblocks = (N_ATOM * 64 + 255) / 256;  // one wave per atom
        if (packed)
            reduce_kernel<true><<<rblocks, 256, 0, stream>>>(cnt, bucket, pack, dist, diff, fc, out);
        else
            reduce_kernel<false><<<rblocks, 256, 0, stream>>>(cnt, bucket, pack, dist, diff, fc, out);
        fin_kernel<<<(N_PAIR + 255) / 256, 256, 0, stream>>>(out);
    } else {
        // fallback: atomic path
        init_kernel<<<(N_PAIR + 255) / 256, 256, 0, stream>>>(out);
        tri_kernel<<<(N_TRI + 255) / 256, 256, 0, stream>>>(ind2, ind3, dist, diff, fc, out);
        fin_kernel<<<(N_PAIR + 255) / 256, 256, 0, stream>>>(out);
    }
}

// Round 3
// 480.392 us; speedup vs baseline: 5.8675x; 1.1350x over previous
//
#include <hip/hip_runtime.h>

#define N_ATOM 30000
#define N_PAIR 1000000
#define N_TRI  4000000
#define N_SF   16
#define FP_ELEMS (N_ATOM * N_SF)   // 480000 floats
#define CAP 192
#define OVF_CAP 262144
#define OVF_CNT_IDX 30720          // lives in the cnt region's padding

__device__ __constant__ float c_eta[16] = {
    0.01f, 0.014f, 0.02f, 0.028f, 0.04f, 0.056f, 0.08f, 0.11f,
    0.16f, 0.22f, 0.32f, 0.45f, 0.63f, 0.72f, 0.9f, 1.0f};

// ---------------------------------------------------------------------------
// workspace layout (bytes):
//   cnt    @ 0        : 128 KiB  (30000 counters + ovf counter at idx 30720)
//   ikmax  @ 131072   : 4 MiB    (int per pair, ik-side segment max)
//   a_of_p @ 4325376  : 4 MiB    (int per pair: ind2[2p])
//   flag   @ 8519680  : 1 MiB    (byte per pair: unmasked ij-appearance)
//   ovf    @ 9568256  : 2 MiB    (int2 overflow triplet list)
//   bucket @ 11665408 : 46.08 MB (int2 * N_ATOM * CAP)
//   pack   @ 57745408 : 16 MB    (float4 {dx,dy,dz,fc} per pair)  [tier0 only]
#define OFF_IKMAX  131072
#define OFF_AOFP   4325376
#define OFF_FLAG   8519680
#define OFF_OVF    9568256
#define OFF_BUCKET 11665408ULL
#define NEED_T1    57745408ULL   // through bucket
#define NEED_T0    73745408ULL   // + pack

// ---------------------------------------------------------------------------

template <bool PACKED>
__global__ __launch_bounds__(256) void prep_kernel(
    const int* __restrict__ ind2, const float* __restrict__ diff,
    const float* __restrict__ fc,
    int* __restrict__ cnt, int* __restrict__ ikmax, int* __restrict__ a_of_p,
    unsigned char* __restrict__ flag, float4* __restrict__ pack)
{
    int p = blockIdx.x * blockDim.x + threadIdx.x;
    if (p < N_ATOM) cnt[p] = 0;
    if (p == 0) cnt[OVF_CNT_IDX] = 0;
    if (p >= N_PAIR) return;
    ikmax[p] = -1;
    flag[p] = 0;
    a_of_p[p] = ind2[2 * p];
    if (PACKED) {
        float4 r;
        r.x = diff[3 * p + 0];
        r.y = diff[3 * p + 1];
        r.z = diff[3 * p + 2];
        r.w = fc[p];
        pack[p] = r;
    }
}

__global__ __launch_bounds__(256) void bin_kernel(
    const int2* __restrict__ ind3, const int* __restrict__ a_of_p,
    int* __restrict__ cnt, int2* __restrict__ bucket, int2* __restrict__ ovf)
{
    int t = blockIdx.x * blockDim.x + threadIdx.x;
    if (t >= N_TRI) return;
    int2 pr = ind3[t];
    int atom = a_of_p[pr.x];
    int slot = atomicAdd(&cnt[atom], 1);
    if (slot < CAP) {
        bucket[(size_t)atom * CAP + slot] = pr;
    } else {
        int o = atomicAdd(&cnt[OVF_CNT_IDX], 1);
        if (o < OVF_CAP) ovf[o] = pr;
    }
}

// Shared per-triplet math. Returns false if masked.
template <bool PACKED>
__device__ __forceinline__ bool tri_math(
    int ij, int ik, const float4* __restrict__ pack,
    const float* __restrict__ dist, const float* __restrict__ diff,
    const float* __restrict__ fc, float A8[8], float& R2)
{
    float ax, ay, az, fcij, bx, by, bz, fcik, d2ij, d2ik, dij, dik;
    if (PACKED) {
        float4 A = pack[ij];
        float4 B = pack[ik];
        ax = A.x; ay = A.y; az = A.z; fcij = A.w;
        bx = B.x; by = B.y; bz = B.z; fcik = B.w;
        d2ij = fmaf(ax, ax, fmaf(ay, ay, az * az));
        d2ik = fmaf(bx, bx, fmaf(by, by, bz * bz));
        dij = sqrtf(d2ij);
        dik = sqrtf(d2ik);
    } else {
        ax = diff[3 * ij + 0]; ay = diff[3 * ij + 1]; az = diff[3 * ij + 2];
        bx = diff[3 * ik + 0]; by = diff[3 * ik + 1]; bz = diff[3 * ik + 2];
        dij = dist[ij]; dik = dist[ik];
        fcij = fc[ij]; fcik = fc[ik];
        d2ij = dij * dij; d2ik = dik * dik;
    }
    float jx = bx - ax, jy = by - ay, jz = bz - az;
    float d2jk = fmaf(jx, jx, fmaf(jy, jy, jz * jz));
    if (!(d2jk < 36.0f)) return false;

    float djk = sqrtf(d2jk);
    const float PI_OVER_RC = 0.5235987755982988f;
    float fcjk = 0.5f * (__cosf(PI_OVER_RC * djk) + 1.0f);
    float dot = fmaf(ax, bx, fmaf(ay, by, az * bz));
    float cosv = dot / (dij * dik);
    R2 = d2ij + d2ik + d2jk;
    float FCt = fcij * fcik * fcjk;

    float bm = fmaxf(1.0f - cosv, 0.0f);
    float bp = fmaxf(1.0f + cosv, 0.0f);
    float bm2 = bm * bm, bp2 = bp * bp;
    float bm4 = bm2 * bm2, bp4 = bp2 * bp2;
    float bm8 = bm4 * bm4, bp8 = bp4 * bp4;
    A8[0] = FCt * bm;
    A8[1] = FCt * bp;
    A8[2] = 0.5f * FCt * bm2;
    A8[3] = 0.5f * FCt * bp2;
    A8[4] = 0.125f * FCt * bm4;
    A8[5] = 0.125f * FCt * bp4;
    A8[6] = 0.0078125f * FCt * bm8;
    A8[7] = 0.0078125f * FCt * bp8;
    return true;
}

// one wave per atom; plain-store the 16-channel row.
template <bool PACKED>
__global__ __launch_bounds__(256) void reduce_kernel(
    const int* __restrict__ cnt, const int2* __restrict__ bucket,
    const float4* __restrict__ pack,
    const float* __restrict__ dist, const float* __restrict__ diff,
    const float* __restrict__ fc,
    int* __restrict__ ikmax, unsigned char* __restrict__ flag,
    float* __restrict__ out)
{
    int wave = (blockIdx.x * blockDim.x + threadIdx.x) >> 6;
    int lane = threadIdx.x & 63;
    if (wave >= N_ATOM) return;
    const int atom = wave;
    int n = cnt[atom];
    if (n > CAP) n = CAP;
    const int2* seg = bucket + (size_t)atom * CAP;

    float acc[16];
#pragma unroll
    for (int s = 0; s < 16; ++s) acc[s] = 0.0f;

    for (int i = lane; i < n; i += 64) {
        int2 pr = seg[i];
        int ij = pr.x, ik = pr.y;
        float A8[8], R2;
        if (!tri_math<PACKED>(ij, ik, pack, dist, diff, fc, A8, R2)) continue;
        flag[ij] = 1;                      // idempotent ij-side marker
        atomicMax(&ikmax[ik], atom);       // ik-side segment max
#pragma unroll
        for (int s = 0; s < 16; ++s)
            acc[s] += A8[s & 7] * __expf(-c_eta[s] * R2);
    }

#pragma unroll
    for (int s = 0; s < 16; ++s) {
        float v = acc[s];
#pragma unroll
        for (int o = 32; o > 0; o >>= 1) v += __shfl_down(v, o);
        acc[s] = v;
    }
    if (lane == 0) {
        float4* dst = (float4*)(out + (size_t)atom * N_SF);
        dst[0] = make_float4(acc[0], acc[1], acc[2], acc[3]);
        dst[1] = make_float4(acc[4], acc[5], acc[6], acc[7]);
        dst[2] = make_float4(acc[8], acc[9], acc[10], acc[11]);
        dst[3] = make_float4(acc[12], acc[13], acc[14], acc[15]);
    }
}

// exact handling of bucket-overflow triplets (runs AFTER reduce's plain stores)
template <bool PACKED>
__global__ __launch_bounds__(256) void ovf_kernel(
    const int* __restrict__ cnt, const int2* __restrict__ ovf,
    const float4* __restrict__ pack,
    const float* __restrict__ dist, const float* __restrict__ diff,
    const float* __restrict__ fc, const int* __restrict__ a_of_p,
    int* __restrict__ ikmax, unsigned char* __restrict__ flag,
    float* __restrict__ out)
{
    int i = blockIdx.x * blockDim.x + threadIdx.x;
    int n = cnt[OVF_CNT_IDX];
    if (n > OVF_CAP) n = OVF_CAP;
    if (i >= n) return;
    int2 pr = ovf[i];
    int ij = pr.x, ik = pr.y;
    float A8[8], R2;
    if (!tri_math<PACKED>(ij, ik, pack, dist, diff, fc, A8, R2)) return;
    int atom = a_of_p[ij];
    flag[ij] = 1;
    atomicMax(&ikmax[ik], atom);
    float* base = out + (size_t)atom * N_SF;
#pragma unroll
    for (int s = 0; s < 16; ++s)
        unsafeAtomicAdd(base + s, A8[s & 7] * __expf(-c_eta[s] * R2));
}

__global__ __launch_bounds__(256) void fin2_kernel(
    const int* __restrict__ ikmax, const unsigned char* __restrict__ flag,
    const int* __restrict__ a_of_p, float* __restrict__ out)
{
    int p = blockIdx.x * blockDim.x + threadIdx.x;
    if (p >= N_PAIR) return;
    int v = ikmax[p];
    if (flag[p]) { int a = a_of_p[p]; v = v > a ? v : a; }
    float* jf = out + FP_ELEMS;
    jf[2 * p + 0] = (float)p;
    jf[2 * p + 1] = (float)v;
}

// ---------------------------------------------------------------------------
// Tier-2 fallback: round-1 atomic path (no workspace requirement)
// ---------------------------------------------------------------------------

__global__ __launch_bounds__(256) void init_kernel(float* __restrict__ out) {
    int i = blockIdx.x * blockDim.x + threadIdx.x;
    if (i < FP_ELEMS) out[i] = 0.0f;
    if (i < N_PAIR) {
        int* jac = (int*)out + FP_ELEMS;
        jac[2 * i + 1] = -1;
    }
}

__global__ __launch_bounds__(256) void tri_kernel(
    const int* __restrict__ ind2, const int2* __restrict__ ind3,
    const float* __restrict__ dist, const float* __restrict__ diff,
    const float* __restrict__ fc, float* __restrict__ out) {
    int t = blockIdx.x * blockDim.x + threadIdx.x;
    if (t >= N_TRI) return;
    int2 pr = ind3[t];
    int ij = pr.x, ik = pr.y;
    float A8[8], R2;
    if (!tri_math<false>(ij, ik, nullptr, dist, diff, fc, A8, R2)) return;
    int atom = ind2[2 * ij];
    int* jac = (int*)out + FP_ELEMS;
    atomicMax(&jac[2 * ij + 1], atom);
    atomicMax(&jac[2 * ik + 1], atom);
    float* base = out + (size_t)atom * N_SF;
#pragma unroll
    for (int s = 0; s < 16; ++s)
        unsafeAtomicAdd(base + s, A8[s & 7] * __expf(-c_eta[s] * R2));
}

__global__ __launch_bounds__(256) void fin_legacy_kernel(float* __restrict__ out) {
    int p = blockIdx.x * blockDim.x + threadIdx.x;
    if (p >= N_PAIR) return;
    int* jac = (int*)out + FP_ELEMS;
    int v = jac[2 * p + 1];
    float* jf = (float*)jac;
    jf[2 * p + 0] = (float)p;
    jf[2 * p + 1] = (float)v;
}

// ---------------------------------------------------------------------------

extern "C" void kernel_launch(void* const* d_in, const int* in_sizes, int n_in,
                              void* d_out, int out_size, void* d_ws, size_t ws_size,
                              hipStream_t stream) {
    const int*   ind2 = (const int*)d_in[0];
    const int2*  ind3 = (const int2*)d_in[1];
    const float* dist = (const float*)d_in[2];
    const float* diff = (const float*)d_in[3];
    const float* fc   = (const float*)d_in[5];
    float* out = (float*)d_out;

    if (ws_size >= NEED_T1) {
        char* ws = (char*)d_ws;
        int* cnt            = (int*)ws;
        int* ikmax          = (int*)(ws + OFF_IKMAX);
        int* a_of_p         = (int*)(ws + OFF_AOFP);
        unsigned char* flag = (unsigned char*)(ws + OFF_FLAG);
        int2* ovf           = (int2*)(ws + OFF_OVF);
        int2* bucket        = (int2*)(ws + OFF_BUCKET);
        float4* pack        = (float4*)(ws + NEED_T1);
        bool packed = (ws_size >= NEED_T0);

        int pb = (N_PAIR + 255) / 256;
        if (packed)
            prep_kernel<true><<<pb, 256, 0, stream>>>(ind2, diff, fc, cnt, ikmax, a_of_p, flag, pack);
        else
            prep_kernel<false><<<pb, 256, 0, stream>>>(ind2, diff, fc, cnt, ikmax, a_of_p, flag, pack);
        bin_kernel<<<(N_TRI + 255) / 256, 256, 0, stream>>>(ind3, a_of_p, cnt, bucket, ovf);
        int rblocks = (N_ATOM * 64) / 256;  // one wave per atom
        if (packed) {
            reduce_kernel<true><<<rblocks, 256, 0, stream>>>(cnt, bucket, pack, dist, diff, fc, ikmax, flag, out);
            ovf_kernel<true><<<OVF_CAP / 256, 256, 0, stream>>>(cnt, ovf, pack, dist, diff, fc, a_of_p, ikmax, flag, out);
        } else {
            reduce_kernel<false><<<rblocks, 256, 0, stream>>>(cnt, bucket, pack, dist, diff, fc, ikmax, flag, out);
            ovf_kernel<false><<<OVF_CAP / 256, 256, 0, stream>>>(cnt, ovf, pack, dist, diff, fc, a_of_p, ikmax, flag, out);
        }
        fin2_kernel<<<pb, 256, 0, stream>>>(ikmax, flag, a_of_p, out);
    } else {
        init_kernel<<<(N_PAIR + 255) / 256, 256, 0, stream>>>(out);
        tri_kernel<<<(N_TRI + 255) / 256, 256, 0, stream>>>(ind2, ind3, dist, diff, fc, out);
        fin_legacy_kernel<<<(N_PAIR + 255) / 256, 256, 0, stream>>>(out);
    }
}

// Round 4
// 458.472 us; speedup vs baseline: 6.1481x; 1.0478x over previous
//
#include <hip/hip_runtime.h>

#define N_ATOM 30000
#define N_PAIR 1000000
#define N_TRI  4000000
#define N_SF   16
#define FP_ELEMS (N_ATOM * N_SF)

#define ASH  5                      // atoms per coarse bucket = 32
#define APB  32
#define NCB  938                    // ceil(30000/32)
#define NSUB 8                      // XCD sub-buckets
#define NSEG (NCB * NSUB)           // 7504
#define OVF_CNT_IDX NSEG
#define OVF_CAP 131072
#define TILE 4096
#define PER_TH 16
#define NTILES ((N_TRI + TILE - 1) / TILE)   // 977

// workspace layout (bytes)
#define OFF_CCNT  0ULL              //  32 KiB: NSEG+1 ints
#define OFF_IKMAX 65536ULL          //  4,000,000  (int per pair)
#define OFF_AOFP  4065536ULL        //  2,000,000  (ushort per pair)
#define OFF_FLAG  6065536ULL        //  1,000,000  (byte per pair)
#define OFF_OVF   7065536ULL        //  1,048,576  (int2 * 131072)
#define OFF_PACK  8114112ULL        // 16,000,000  (float4 {dx,dy,dz,fc})
#define OFF_CB    24114112ULL       // cbucket: NSEG * cap * 8

__device__ __constant__ float c_eta[16] = {
    0.01f, 0.014f, 0.02f, 0.028f, 0.04f, 0.056f, 0.08f, 0.11f,
    0.16f, 0.22f, 0.32f, 0.45f, 0.63f, 0.72f, 0.9f, 1.0f};

// ---------------------------------------------------------------------------
// shared triplet math (pack record = {dx,dy,dz,fc})
// ---------------------------------------------------------------------------
__device__ __forceinline__ bool tri_math_pack(
    float4 A, float4 B, float A8[8], float& R2)
{
    float ax = A.x, ay = A.y, az = A.z, fcij = A.w;
    float bx = B.x, by = B.y, bz = B.z, fcik = B.w;
    float d2ij = fmaf(ax, ax, fmaf(ay, ay, az * az));
    float d2ik = fmaf(bx, bx, fmaf(by, by, bz * bz));
    float jx = bx - ax, jy = by - ay, jz = bz - az;
    float d2jk = fmaf(jx, jx, fmaf(jy, jy, jz * jz));
    if (!(d2jk < 36.0f)) return false;
    float dij = sqrtf(d2ij);
    float dik = sqrtf(d2ik);
    float djk = sqrtf(d2jk);
    const float PI_OVER_RC = 0.5235987755982988f;
    float fcjk = 0.5f * (__cosf(PI_OVER_RC * djk) + 1.0f);
    float dot = fmaf(ax, bx, fmaf(ay, by, az * bz));
    float cosv = dot / (dij * dik);
    R2 = d2ij + d2ik + d2jk;
    float FCt = fcij * fcik * fcjk;
    float bm = fmaxf(1.0f - cosv, 0.0f);
    float bp = fmaxf(1.0f + cosv, 0.0f);
    float bm2 = bm * bm, bp2 = bp * bp;
    float bm4 = bm2 * bm2, bp4 = bp2 * bp2;
    float bm8 = bm4 * bm4, bp8 = bp4 * bp4;
    A8[0] = FCt * bm;              A8[1] = FCt * bp;
    A8[2] = 0.5f * FCt * bm2;      A8[3] = 0.5f * FCt * bp2;
    A8[4] = 0.125f * FCt * bm4;    A8[5] = 0.125f * FCt * bp4;
    A8[6] = 0.0078125f * FCt * bm8; A8[7] = 0.0078125f * FCt * bp8;
    return true;
}

// ---------------------------------------------------------------------------
// fast path
// ---------------------------------------------------------------------------

__global__ __launch_bounds__(256) void prep2(
    const int2* __restrict__ ind2, const float* __restrict__ diff,
    const float* __restrict__ fc,
    int* __restrict__ ccnt, int* __restrict__ ikmax,
    unsigned short* __restrict__ aofp, unsigned char* __restrict__ flag,
    float4* __restrict__ pack)
{
    int p = blockIdx.x * blockDim.x + threadIdx.x;
    if (p <= NSEG) ccnt[p] = 0;     // includes overflow counter
    if (p >= N_PAIR) return;
    ikmax[p] = -1;
    flag[p] = 0;
    aofp[p] = (unsigned short)ind2[p].x;
    float4 r;
    r.x = diff[3 * p + 0];
    r.y = diff[3 * p + 1];
    r.z = diff[3 * p + 2];
    r.w = fc[p];
    pack[p] = r;
}

// LDS-staged counting scatter into coarse buckets (XCD sub-bucketed).
__global__ __launch_bounds__(256) void bin3(
    const int2* __restrict__ ind3, const unsigned short* __restrict__ aofp,
    int* __restrict__ ccnt, int2* __restrict__ cbucket,
    int2* __restrict__ ovf, int cap)
{
    __shared__ int lcnt[NCB];
    __shared__ int lbase[NCB];
    const int thr = threadIdx.x;
    const int sub = blockIdx.x & (NSUB - 1);
    const long long t0 = (long long)blockIdx.x * TILE;

    for (int i = thr; i < NCB; i += 256) lcnt[i] = 0;
    __syncthreads();

    int myatom[PER_TH];
    int myslot[PER_TH];
#pragma unroll
    for (int j = 0; j < PER_TH; ++j) {
        long long t = t0 + j * 256 + thr;
        int a = 0, s = -1;
        if (t < N_TRI) {
            int ij = ind3[t].x;
            a = aofp[ij];
            s = atomicAdd(&lcnt[a >> ASH], 1);
        }
        myatom[j] = a;
        myslot[j] = s;
    }
    __syncthreads();
    for (int c = thr; c < NCB; c += 256) {
        int n = lcnt[c];
        lbase[c] = n ? atomicAdd(&ccnt[c * NSUB + sub], n) : 0;
    }
    __syncthreads();
#pragma unroll
    for (int j = 0; j < PER_TH; ++j) {
        long long t = t0 + j * 256 + thr;
        if (t >= N_TRI) continue;
        int a = myatom[j];
        int c = a >> ASH;
        int slot = lbase[c] + myslot[j];
        int2 pr = ind3[t];
        if (slot < cap) {
            int2 e;
            e.x = pr.x | ((a & (APB - 1)) << 20);   // ij < 2^20, pack a5 above
            e.y = pr.y;
            cbucket[(size_t)(c * NSUB + sub) * cap + slot] = e;
        } else {
            int o = atomicAdd(&ccnt[OVF_CNT_IDX], 1);
            if (o < OVF_CAP) ovf[o] = pr;
        }
    }
}

// one block per coarse bucket: LDS float accumulation, plain row stores.
__global__ __launch_bounds__(256) void reduce3(
    const int* __restrict__ ccnt, const int2* __restrict__ cbucket, int cap,
    const float4* __restrict__ pack,
    int* __restrict__ ikmax, unsigned char* __restrict__ flag,
    float* __restrict__ out)
{
    __shared__ float lacc[APB * 17];      // +1 pad per atom row: bank spread
    const int b = blockIdx.x;
    const int thr = threadIdx.x;
    for (int i = thr; i < APB * 17; i += 256) lacc[i] = 0.0f;
    __syncthreads();

    for (int sub = 0; sub < NSUB; ++sub) {
        int n = ccnt[b * NSUB + sub];
        n = min(n, cap);
        const int2* seg = cbucket + (size_t)(b * NSUB + sub) * cap;
        for (int i = thr; i < n; i += 256) {
            int2 e = seg[i];
            int a5 = (e.x >> 20) & (APB - 1);
            int ij = e.x & 0xFFFFF;
            int ik = e.y;
            float4 A = pack[ij];
            float4 B = pack[ik];
            float A8[8], R2;
            if (!tri_math_pack(A, B, A8, R2)) continue;
            flag[ij] = 1;
            atomicMax(&ikmax[ik], (b << ASH) + a5);
#pragma unroll
            for (int s = 0; s < 16; ++s)
                atomicAdd(&lacc[a5 * 17 + s], A8[s & 7] * __expf(-c_eta[s] * R2));
        }
    }
    __syncthreads();
    for (int t = thr; t < APB * N_SF; t += 256) {
        int atom = (b << ASH) + (t >> 4);
        if (atom < N_ATOM)
            out[(size_t)atom * N_SF + (t & 15)] = lacc[(t >> 4) * 17 + (t & 15)];
    }
}

// exact path for bucket-overflow triplets (after reduce3's plain stores)
__global__ __launch_bounds__(256) void ovf3(
    const int* __restrict__ ccnt, const int2* __restrict__ ovf,
    const float4* __restrict__ pack, const unsigned short* __restrict__ aofp,
    int* __restrict__ ikmax, unsigned char* __restrict__ flag,
    float* __restrict__ out)
{
    int i = blockIdx.x * blockDim.x + threadIdx.x;
    int n = ccnt[OVF_CNT_IDX];
    if (n > OVF_CAP) n = OVF_CAP;
    if (i >= n) return;
    int2 pr = ovf[i];
    int ij = pr.x, ik = pr.y;
    float A8[8], R2;
    if (!tri_math_pack(pack[ij], pack[ik], A8, R2)) return;
    int atom = aofp[ij];
    flag[ij] = 1;
    atomicMax(&ikmax[ik], atom);
    float* base = out + (size_t)atom * N_SF;
#pragma unroll
    for (int s = 0; s < 16; ++s)
        unsafeAtomicAdd(base + s, A8[s & 7] * __expf(-c_eta[s] * R2));
}

__global__ __launch_bounds__(256) void fin3(
    const int* __restrict__ ikmax, const unsigned char* __restrict__ flag,
    const unsigned short* __restrict__ aofp, float* __restrict__ out)
{
    int p = blockIdx.x * blockDim.x + threadIdx.x;
    if (p >= N_PAIR) return;
    int v = ikmax[p];
    if (flag[p]) { int a = aofp[p]; v = v > a ? v : a; }
    float* jf = out + FP_ELEMS;
    jf[2 * p + 0] = (float)p;
    jf[2 * p + 1] = (float)v;
}

// ---------------------------------------------------------------------------
// legacy fallback (no workspace requirement beyond none)
// ---------------------------------------------------------------------------

__device__ __forceinline__ bool tri_math_raw(
    int ij, int ik, const float* dist, const float* diff, const float* fc,
    float A8[8], float& R2)
{
    float4 A, B;
    A.x = diff[3 * ij + 0]; A.y = diff[3 * ij + 1]; A.z = diff[3 * ij + 2]; A.w = fc[ij];
    B.x = diff[3 * ik + 0]; B.y = diff[3 * ik + 1]; B.z = diff[3 * ik + 2]; B.w = fc[ik];
    return tri_math_pack(A, B, A8, R2);
}

__global__ __launch_bounds__(256) void init_legacy(float* __restrict__ out) {
    int i = blockIdx.x * blockDim.x + threadIdx.x;
    if (i < FP_ELEMS) out[i] = 0.0f;
    if (i < N_PAIR) ((int*)out + FP_ELEMS)[2 * i + 1] = -1;
}

__global__ __launch_bounds__(256) void tri_legacy(
    const int* __restrict__ ind2, const int2* __restrict__ ind3,
    const float* __restrict__ dist, const float* __restrict__ diff,
    const float* __restrict__ fc, float* __restrict__ out) {
    int t = blockIdx.x * blockDim.x + threadIdx.x;
    if (t >= N_TRI) return;
    int2 pr = ind3[t];
    int ij = pr.x, ik = pr.y;
    float A8[8], R2;
    if (!tri_math_raw(ij, ik, dist, diff, fc, A8, R2)) return;
    int atom = ind2[2 * ij];
    int* jac = (int*)out + FP_ELEMS;
    atomicMax(&jac[2 * ij + 1], atom);
    atomicMax(&jac[2 * ik + 1], atom);
    float* base = out + (size_t)atom * N_SF;
#pragma unroll
    for (int s = 0; s < 16; ++s)
        unsafeAtomicAdd(base + s, A8[s & 7] * __expf(-c_eta[s] * R2));
}

__global__ __launch_bounds__(256) void fin_legacy(float* __restrict__ out) {
    int p = blockIdx.x * blockDim.x + threadIdx.x;
    if (p >= N_PAIR) return;
    int* jac = (int*)out + FP_ELEMS;
    int v = jac[2 * p + 1];
    float* jf = (float*)jac;
    jf[2 * p + 0] = (float)p;
    jf[2 * p + 1] = (float)v;
}

// ---------------------------------------------------------------------------

extern "C" void kernel_launch(void* const* d_in, const int* in_sizes, int n_in,
                              void* d_out, int out_size, void* d_ws, size_t ws_size,
                              hipStream_t stream) {
    const int2*  ind2 = (const int2*)d_in[0];
    const int2*  ind3 = (const int2*)d_in[1];
    const float* dist = (const float*)d_in[2];
    const float* diff = (const float*)d_in[3];
    const float* fc   = (const float*)d_in[5];
    float* out = (float*)d_out;

    const size_t seg_stride = (size_t)NSEG * sizeof(int2);
    const size_t need_min = OFF_CB + seg_stride * 608;   // cap >= 608 (3.3 sigma)

    if (ws_size >= need_min) {
        char* ws = (char*)d_ws;
        int* ccnt            = (int*)(ws + OFF_CCNT);
        int* ikmax           = (int*)(ws + OFF_IKMAX);
        unsigned short* aofp = (unsigned short*)(ws + OFF_AOFP);
        unsigned char* flag  = (unsigned char*)(ws + OFF_FLAG);
        int2* ovf            = (int2*)(ws + OFF_OVF);
        float4* pack         = (float4*)(ws + OFF_PACK);
        int2* cbucket        = (int2*)(ws + OFF_CB);
        int cap = (int)((ws_size - OFF_CB) / seg_stride);
        if (cap > 1024) cap = 1024;

        int pb = (N_PAIR + 255) / 256;
        prep2<<<pb, 256, 0, stream>>>(ind2, diff, fc, ccnt, ikmax, aofp, flag, pack);
        bin3<<<NTILES, 256, 0, stream>>>(ind3, aofp, ccnt, cbucket, ovf, cap);
        reduce3<<<NCB, 256, 0, stream>>>(ccnt, cbucket, cap, pack, ikmax, flag, out);
        ovf3<<<OVF_CAP / 256, 256, 0, stream>>>(ccnt, ovf, pack, aofp, ikmax, flag, out);
        fin3<<<pb, 256, 0, stream>>>(ikmax, flag, aofp, out);
    } else {
        init_legacy<<<(N_PAIR + 255) / 256, 256, 0, stream>>>(out);
        tri_legacy<<<(N_TRI + 255) / 256, 256, 0, stream>>>((const int*)d_in[0], ind3, dist, diff, fc, out);
        fin_legacy<<<(N_PAIR + 255) / 256, 256, 0, stream>>>(out);
    }
}

// Round 5
// 447.453 us; speedup vs baseline: 6.2995x; 1.0246x over previous
//
#include <hip/hip_runtime.h>

#define N_ATOM 30000
#define N_PAIR 1000000
#define N_TRI  4000000
#define N_SF   16
#define FP_ELEMS (N_ATOM * N_SF)

#define ASH  5                      // atoms per coarse bucket = 32
#define APB  32
#define NCB  938                    // ceil(30000/32)
#define NSUB 8                      // XCD sub-buckets
#define NSEG (NCB * NSUB)           // 7504
#define OVF_CNT_IDX NSEG
#define OVF_CAP 131072
#define TILE 4096
#define PER_TH 16
#define NTILES ((N_TRI + TILE - 1) / TILE)   // 977

// workspace layout (bytes)
#define OFF_CCNT  0ULL              //  32 KiB: NSEG+1 ints
#define OFF_IKMAX 65536ULL          //  4,000,000  (int per pair)
#define OFF_AOFP  4065536ULL        //  2,000,000  (ushort per pair)
#define OFF_FLAG  6065536ULL        //  1,000,000  (byte per pair)
#define OFF_OVF   7065536ULL        //  1,048,576  (int2 * 131072)
#define OFF_PACK  8114112ULL        // 16,000,000  (float4 {dx,dy,dz,fc})
#define OFF_CB    24114112ULL       // cbucket: NSEG * cap * 8

__device__ __constant__ float c_eta[16] = {
    0.01f, 0.014f, 0.02f, 0.028f, 0.04f, 0.056f, 0.08f, 0.11f,
    0.16f, 0.22f, 0.32f, 0.45f, 0.63f, 0.72f, 0.9f, 1.0f};

// ---------------------------------------------------------------------------
__device__ __forceinline__ bool tri_math_pack(
    float4 A, float4 B, float A8[8], float& R2)
{
    float ax = A.x, ay = A.y, az = A.z, fcij = A.w;
    float bx = B.x, by = B.y, bz = B.z, fcik = B.w;
    float d2ij = fmaf(ax, ax, fmaf(ay, ay, az * az));
    float d2ik = fmaf(bx, bx, fmaf(by, by, bz * bz));
    float jx = bx - ax, jy = by - ay, jz = bz - az;
    float d2jk = fmaf(jx, jx, fmaf(jy, jy, jz * jz));
    if (!(d2jk < 36.0f)) return false;
    float dij = sqrtf(d2ij);
    float dik = sqrtf(d2ik);
    float djk = sqrtf(d2jk);
    const float PI_OVER_RC = 0.5235987755982988f;
    float fcjk = 0.5f * (__cosf(PI_OVER_RC * djk) + 1.0f);
    float dot = fmaf(ax, bx, fmaf(ay, by, az * bz));
    float cosv = dot / (dij * dik);
    R2 = d2ij + d2ik + d2jk;
    float FCt = fcij * fcik * fcjk;
    float bm = fmaxf(1.0f - cosv, 0.0f);
    float bp = fmaxf(1.0f + cosv, 0.0f);
    float bm2 = bm * bm, bp2 = bp * bp;
    float bm4 = bm2 * bm2, bp4 = bp2 * bp2;
    float bm8 = bm4 * bm4, bp8 = bp4 * bp4;
    A8[0] = FCt * bm;              A8[1] = FCt * bp;
    A8[2] = 0.5f * FCt * bm2;      A8[3] = 0.5f * FCt * bp2;
    A8[4] = 0.125f * FCt * bm4;    A8[5] = 0.125f * FCt * bp4;
    A8[6] = 0.0078125f * FCt * bm8; A8[7] = 0.0078125f * FCt * bp8;
    return true;
}

// ---------------------------------------------------------------------------
// fast path
// ---------------------------------------------------------------------------

__global__ __launch_bounds__(256) void prep2(
    const int2* __restrict__ ind2, const float* __restrict__ diff,
    const float* __restrict__ fc,
    int* __restrict__ ccnt, int* __restrict__ ikmax,
    unsigned short* __restrict__ aofp, unsigned char* __restrict__ flag,
    float4* __restrict__ pack, float* __restrict__ out)
{
    int p = blockIdx.x * blockDim.x + threadIdx.x;
    if (p <= NSEG) ccnt[p] = 0;     // includes overflow counter
    if (p < FP_ELEMS) out[p] = 0.0f;  // zero fp rows (reduce4/ovf4 atomic-add)
    if (p >= N_PAIR) return;
    ikmax[p] = -1;
    flag[p] = 0;
    aofp[p] = (unsigned short)ind2[p].x;
    float4 r;
    r.x = diff[3 * p + 0];
    r.y = diff[3 * p + 1];
    r.z = diff[3 * p + 2];
    r.w = fc[p];
    pack[p] = r;
}

// LDS-staged counting scatter into coarse buckets (XCD sub-bucketed).
__global__ __launch_bounds__(256) void bin3(
    const int2* __restrict__ ind3, const unsigned short* __restrict__ aofp,
    int* __restrict__ ccnt, int2* __restrict__ cbucket,
    int2* __restrict__ ovf, int cap)
{
    __shared__ int lcnt[NCB];
    __shared__ int lbase[NCB];
    const int thr = threadIdx.x;
    const int sub = blockIdx.x & (NSUB - 1);
    const long long t0 = (long long)blockIdx.x * TILE;

    for (int i = thr; i < NCB; i += 256) lcnt[i] = 0;
    __syncthreads();

    int myatom[PER_TH];
    int myslot[PER_TH];
#pragma unroll
    for (int j = 0; j < PER_TH; ++j) {
        long long t = t0 + j * 256 + thr;
        int a = 0, s = -1;
        if (t < N_TRI) {
            int ij = ind3[t].x;
            a = aofp[ij];
            s = atomicAdd(&lcnt[a >> ASH], 1);
        }
        myatom[j] = a;
        myslot[j] = s;
    }
    __syncthreads();
    for (int c = thr; c < NCB; c += 256) {
        int n = lcnt[c];
        lbase[c] = n ? atomicAdd(&ccnt[c * NSUB + sub], n) : 0;
    }
    __syncthreads();
#pragma unroll
    for (int j = 0; j < PER_TH; ++j) {
        long long t = t0 + j * 256 + thr;
        if (t >= N_TRI) continue;
        int a = myatom[j];
        int c = a >> ASH;
        int slot = lbase[c] + myslot[j];
        int2 pr = ind3[t];
        if (slot < cap) {
            int2 e;
            e.x = pr.x | ((a & (APB - 1)) << 20);   // ij < 2^20, pack a5 above
            e.y = pr.y;
            cbucket[(size_t)(c * NSUB + sub) * cap + slot] = e;
        } else {
            int o = atomicAdd(&ccnt[OVF_CNT_IDX], 1);
            if (o < OVF_CAP) ovf[o] = pr;
        }
    }
}

// one block per (coarse bucket, sub) segment: 7504 blocks, balanced ~533
// triplets each. LDS accumulate 32x16, epilogue = 512 fire-and-forget
// unsafeAtomicAdd into the zeroed out rows (8 blocks share a row set).
__global__ __launch_bounds__(256) void reduce4(
    const int* __restrict__ ccnt, const int2* __restrict__ cbucket, int cap,
    const float4* __restrict__ pack,
    int* __restrict__ ikmax, unsigned char* __restrict__ flag,
    float* __restrict__ out)
{
    __shared__ float lacc[APB * 17];      // +1 pad per atom row
    const int seg = blockIdx.x;
    const int b = seg >> 3;               // coarse bucket
    const int thr = threadIdx.x;
    for (int i = thr; i < APB * 17; i += 256) lacc[i] = 0.0f;
    __syncthreads();

    int n = ccnt[seg];
    n = min(n, cap);
    const int2* segp = cbucket + (size_t)seg * cap;
    for (int i = thr; i < n; i += 256) {
        int2 e = segp[i];
        int a5 = (e.x >> 20) & (APB - 1);
        int ij = e.x & 0xFFFFF;
        int ik = e.y;
        float4 A = pack[ij];
        float4 B = pack[ik];
        float A8[8], R2;
        if (!tri_math_pack(A, B, A8, R2)) continue;
        flag[ij] = 1;
        atomicMax(&ikmax[ik], (b << ASH) + a5);
#pragma unroll
        for (int s = 0; s < 16; ++s)
            atomicAdd(&lacc[a5 * 17 + s], A8[s & 7] * __expf(-c_eta[s] * R2));
    }
    __syncthreads();
    for (int t = thr; t < APB * N_SF; t += 256) {
        int atom = (b << ASH) + (t >> 4);
        float v = lacc[(t >> 4) * 17 + (t & 15)];
        if (atom < N_ATOM && v != 0.0f)
            unsafeAtomicAdd(out + (size_t)atom * N_SF + (t & 15), v);
    }
}

// exact path for bucket-overflow triplets (atomic adds; order-free vs reduce4)
__global__ __launch_bounds__(256) void ovf3(
    const int* __restrict__ ccnt, const int2* __restrict__ ovf,
    const float4* __restrict__ pack, const unsigned short* __restrict__ aofp,
    int* __restrict__ ikmax, unsigned char* __restrict__ flag,
    float* __restrict__ out)
{
    int i = blockIdx.x * blockDim.x + threadIdx.x;
    int n = ccnt[OVF_CNT_IDX];
    if (n > OVF_CAP) n = OVF_CAP;
    if (i >= n) return;
    int2 pr = ovf[i];
    int ij = pr.x, ik = pr.y;
    float A8[8], R2;
    if (!tri_math_pack(pack[ij], pack[ik], A8, R2)) return;
    int atom = aofp[ij];
    flag[ij] = 1;
    atomicMax(&ikmax[ik], atom);
    float* base = out + (size_t)atom * N_SF;
#pragma unroll
    for (int s = 0; s < 16; ++s)
        unsafeAtomicAdd(base + s, A8[s & 7] * __expf(-c_eta[s] * R2));
}

__global__ __launch_bounds__(256) void fin3(
    const int* __restrict__ ikmax, const unsigned char* __restrict__ flag,
    const unsigned short* __restrict__ aofp, float* __restrict__ out)
{
    int p = blockIdx.x * blockDim.x + threadIdx.x;
    if (p >= N_PAIR) return;
    int v = ikmax[p];
    if (flag[p]) { int a = aofp[p]; v = v > a ? v : a; }
    float* jf = out + FP_ELEMS;
    jf[2 * p + 0] = (float)p;
    jf[2 * p + 1] = (float)v;
}

// ---------------------------------------------------------------------------
// legacy fallback
// ---------------------------------------------------------------------------

__global__ __launch_bounds__(256) void init_legacy(float* __restrict__ out) {
    int i = blockIdx.x * blockDim.x + threadIdx.x;
    if (i < FP_ELEMS) out[i] = 0.0f;
    if (i < N_PAIR) ((int*)out + FP_ELEMS)[2 * i + 1] = -1;
}

__global__ __launch_bounds__(256) void tri_legacy(
    const int* __restrict__ ind2, const int2* __restrict__ ind3,
    const float* __restrict__ dist, const float* __restrict__ diff,
    const float* __restrict__ fc, float* __restrict__ out) {
    int t = blockIdx.x * blockDim.x + threadIdx.x;
    if (t >= N_TRI) return;
    int2 pr = ind3[t];
    int ij = pr.x, ik = pr.y;
    float4 A, B;
    A.x = diff[3 * ij + 0]; A.y = diff[3 * ij + 1]; A.z = diff[3 * ij + 2]; A.w = fc[ij];
    B.x = diff[3 * ik + 0]; B.y = diff[3 * ik + 1]; B.z = diff[3 * ik + 2]; B.w = fc[ik];
    float A8[8], R2;
    if (!tri_math_pack(A, B, A8, R2)) return;
    int atom = ind2[2 * ij];
    int* jac = (int*)out + FP_ELEMS;
    atomicMax(&jac[2 * ij + 1], atom);
    atomicMax(&jac[2 * ik + 1], atom);
    float* base = out + (size_t)atom * N_SF;
#pragma unroll
    for (int s = 0; s < 16; ++s)
        unsafeAtomicAdd(base + s, A8[s & 7] * __expf(-c_eta[s] * R2));
}

__global__ __launch_bounds__(256) void fin_legacy(float* __restrict__ out) {
    int p = blockIdx.x * blockDim.x + threadIdx.x;
    if (p >= N_PAIR) return;
    int* jac = (int*)out + FP_ELEMS;
    int v = jac[2 * p + 1];
    float* jf = (float*)jac;
    jf[2 * p + 0] = (float)p;
    jf[2 * p + 1] = (float)v;
}

// ---------------------------------------------------------------------------

extern "C" void kernel_launch(void* const* d_in, const int* in_sizes, int n_in,
                              void* d_out, int out_size, void* d_ws, size_t ws_size,
                              hipStream_t stream) {
    const int2*  ind2 = (const int2*)d_in[0];
    const int2*  ind3 = (const int2*)d_in[1];
    const float* dist = (const float*)d_in[2];
    const float* diff = (const float*)d_in[3];
    const float* fc   = (const float*)d_in[5];
    float* out = (float*)d_out;

    const size_t seg_stride = (size_t)NSEG * sizeof(int2);
    const size_t need_min = OFF_CB + seg_stride * 608;

    if (ws_size >= need_min) {
        char* ws = (char*)d_ws;
        int* ccnt            = (int*)(ws + OFF_CCNT);
        int* ikmax           = (int*)(ws + OFF_IKMAX);
        unsigned short* aofp = (unsigned short*)(ws + OFF_AOFP);
        unsigned char* flag  = (unsigned char*)(ws + OFF_FLAG);
        int2* ovf            = (int2*)(ws + OFF_OVF);
        float4* pack         = (float4*)(ws + OFF_PACK);
        int2* cbucket        = (int2*)(ws + OFF_CB);
        int cap = (int)((ws_size - OFF_CB) / seg_stride);
        if (cap > 1024) cap = 1024;

        int pb = (N_PAIR + 255) / 256;
        prep2<<<pb, 256, 0, stream>>>(ind2, diff, fc, ccnt, ikmax, aofp, flag, pack, out);
        bin3<<<NTILES, 256, 0, stream>>>(ind3, aofp, ccnt, cbucket, ovf, cap);
        reduce4<<<NSEG, 256, 0, stream>>>(ccnt, cbucket, cap, pack, ikmax, flag, out);
        ovf3<<<OVF_CAP / 256, 256, 0, stream>>>(ccnt, ovf, pack, aofp, ikmax, flag, out);
        fin3<<<pb, 256, 0, stream>>>(ikmax, flag, aofp, out);
    } else {
        init_legacy<<<(N_PAIR + 255) / 256, 256, 0, stream>>>(out);
        tri_legacy<<<(N_PAIR * 4 + 255) / 256, 256, 0, stream>>>((const int*)d_in[0], ind3, dist, diff, fc, out);
        fin_legacy<<<(N_PAIR + 255) / 256, 256, 0, stream>>>(out);
    }
}